// Round 9
// baseline (19702.782 us; speedup 1.0000x reference)
//
#include <hip/hip_runtime.h>
#include <hip/hip_bf16.h>

// LSTM Seq2Seq, fp16 MFMA + fp32 cell state. Round 9: ROW-LOCAL, ZERO-SYNC.
// r1-r8 lesson: any 256-block global sync on MI355X costs 18-30us/phase
// (coherent-point fences/polls/RMW all failed to get below that). But batch
// rows never mix: a block owning 16 batch rows x ALL hidden cols x both
// layers runs the whole 120-step recurrence with NO inter-block
// communication at all. 32 blocks x 1024 threads (16 waves = 4/SIMD).
// Wave w owns hidden cols [w*32,w*32+32) for all 4 gates -> LSTM epilogue
// is wave-local; cell state lives in lane registers (D-layout ownership);
// h0/h1 in LDS (stride 520: 2-way bank alias = free); weights stream via
// normal cached loads (L2/L3-resident). Normal launches, no cooperative.
// Arithmetic: 6272 MFMAs/block/step -> 12.7us/step MFMA-bound; 120 steps
// ~= 1.5-1.7ms predicted.

typedef _Float16 half8 __attribute__((ext_vector_type(8)));
typedef float floatx4 __attribute__((ext_vector_type(4)));

#define NBLK 32
#define NTHR 1024

__device__ __forceinline__ float sigf(float x) { return 1.f / (1.f + __expf(-x)); }
__device__ __forceinline__ float tanhf_(float x) { return 1.f - 2.f / (__expf(2.f * x) + 1.f); }

#define MFMA16(a, b, c) __builtin_amdgcn_mfma_f32_16x16x32_f16((a), (b), (c), 0, 0, 0)

// ---------------- prep kernel: fp16 weight repack + transposes ----------------
__global__ void prep_kernel(
    const float* __restrict__ src,
    const float* __restrict__ eWih0, const float* __restrict__ eWhh0,
    const float* __restrict__ ebih0, const float* __restrict__ ebhh0,
    const float* __restrict__ eWih1, const float* __restrict__ eWhh1,
    const float* __restrict__ ebih1, const float* __restrict__ ebhh1,
    const float* __restrict__ dWih0, const float* __restrict__ dWhh0,
    const float* __restrict__ dbih0, const float* __restrict__ dbhh0,
    const float* __restrict__ dWih1, const float* __restrict__ dWhh1,
    const float* __restrict__ dbih1, const float* __restrict__ dbhh1,
    const float* __restrict__ fc1w, const float* __restrict__ fc1b,
    const float* __restrict__ fc4w, const float* __restrict__ fc4b,
    _Float16* W0e, _Float16* W1e, _Float16* W0d, _Float16* W1d,
    float* bs, _Float16* Xe, _Float16* Wfc, float* bfc)
{
  const int T = gridDim.x * blockDim.x;
  const int idx = blockIdx.x * blockDim.x + threadIdx.x;

  // L0 weights: row r = [Whh0[r][0..511] | Wih0[r][0..31]], stride 544
  for (int i = idx; i < 2048 * 544; i += T) {
    int r = i / 544, k = i - r * 544;
    W0e[i] = (_Float16)(k < 512 ? eWhh0[r * 512 + k] : eWih0[r * 32 + k - 512]);
    W0d[i] = (_Float16)(k < 512 ? dWhh0[r * 512 + k] : dWih0[r * 32 + k - 512]);
  }
  // L1 weights: row r = [Whh1 (k 0..511 <-> h1) | Wih1 (k 512..1023 <-> h0)]
  for (int i = idx; i < 2048 * 1024; i += T) {
    int r = i >> 10, k = i & 1023;
    W1e[i] = (_Float16)(k < 512 ? eWhh1[r * 512 + k] : eWih1[r * 512 + k - 512]);
    W1d[i] = (_Float16)(k < 512 ? dWhh1[r * 512 + k] : dWih1[r * 512 + k - 512]);
  }
  // combined biases bih+bhh: [b0e | b1e | b0d | b1d]
  for (int i = idx; i < 2048; i += T) {
    bs[i]        = ebih0[i] + ebhh0[i];
    bs[2048 + i] = ebih1[i] + ebhh1[i];
    bs[4096 + i] = dbih0[i] + dbhh0[i];
    bs[6144 + i] = dbih1[i] + dbhh1[i];
  }
  // FC weights: rows 0..31 = fc4w, row 32 = fc1w, rows 33..47 zero
  for (int i = idx; i < 48 * 512; i += T) {
    int r = i >> 9, k = i & 511;
    float v = (r < 32) ? fc4w[r * 512 + k] : (r == 32 ? fc1w[k] : 0.f);
    Wfc[i] = (_Float16)v;
  }
  for (int i = idx; i < 64; i += T)
    bfc[i] = (i < 32) ? fc4b[i] : (i == 32 ? fc1b[0] : 0.f);
  // encoder inputs step-major: Xe[t][b][f] = src[b][t][f]
  for (int i = idx; i < 96 * 512 * 32; i += T) {
    int t = i / (512 * 32); int rem = i - t * 512 * 32; int b = rem >> 5; int f = rem & 31;
    Xe[i] = (_Float16)src[(size_t)b * 96 * 32 + t * 32 + f];
  }
}

// LDS accessors (row-major, padded strides chosen for 2-way-max bank alias)
#define H0S(r, k) h0s[(r) * 520 + (k)]
#define H1S(r, k) h1s[(r) * 520 + (k)]
#define XLS(r, k) xls[(r) * 40 + (k)]

// ---------------- the whole network, one block per 16 batch rows ----------------
__global__ void __launch_bounds__(NTHR, 1) lstm_main(
    const _Float16* __restrict__ W0e, const _Float16* __restrict__ W1e,
    const _Float16* __restrict__ W0d, const _Float16* __restrict__ W1d,
    const float* __restrict__ bs, const _Float16* __restrict__ Xe,
    const _Float16* __restrict__ Wfc, const float* __restrict__ bfc,
    float* __restrict__ out)
{
  const int tid = threadIdx.x;
  const int lane = tid & 63, wv = tid >> 6;        // 16 waves
  const int row0 = (int)blockIdx.x * 16;           // batch slab
  const int wcol = wv * 32;                        // wave's hidden cols
  const int row_a = lane & 15, kq = lane >> 4, kq8 = kq * 8;

  __shared__ _Float16 h0s[16 * 520];
  __shared__ _Float16 h1s[16 * 520];
  __shared__ _Float16 xls[16 * 40];
  for (int i = tid; i < 16 * 520; i += NTHR) { h0s[i] = (_Float16)0.f; h1s[i] = (_Float16)0.f; }
  __syncthreads();

  // cell state in registers: c[nt][j] for (row kq*4+j, col wcol+nt*16+row_a)
  float c0r[2][4] = {{0.f,0.f,0.f,0.f},{0.f,0.f,0.f,0.f}};
  float c1r[2][4] = {{0.f,0.f,0.f,0.f},{0.f,0.f,0.f,0.f}};

  for (int s = 0; s < 120; ++s) {
    const bool enc = (s < 96);
    const _Float16* W0 = enc ? W0e : W0d;
    const _Float16* W1 = enc ? W1e : W1d;
    const float* bs0 = bs + (enc ? 0 : 4096);
    const float* bs1 = bs + (enc ? 2048 : 6144);

    // x A-fragment: encoder + first decoder step from global Xe, rest from xls
    half8 ax;
    if (s <= 96) {
      int tx = (s == 96) ? 95 : s;   // x_init = src[:,95,:] = Xe[95]
      ax = *(const half8*)(Xe + ((size_t)tx * 512 + row0 + row_a) * 32 + kq8);
    } else {
      ax = *(const half8*)(&XLS(row_a, kq8));
    }

    // ---- L0: z0 = h0_prev @ Whh0^T + x @ Wih0^T ----
    floatx4 a0[4][2];
#pragma unroll
    for (int g = 0; g < 4; ++g)
#pragma unroll
      for (int nt = 0; nt < 2; ++nt) {
        float b = bs0[g * 512 + wcol + nt * 16 + row_a];
        a0[g][nt] = (floatx4){b, b, b, b};
      }
#pragma unroll
    for (int gp = 0; gp < 2; ++gp) {   // gate pairs to bound VGPR pressure
      const int g0 = gp * 2;
      const _Float16* b00 = W0 + (size_t)(g0 * 512 + wcol + row_a) * 544 + kq8;
      const _Float16* b01 = W0 + (size_t)(g0 * 512 + wcol + 16 + row_a) * 544 + kq8;
      const _Float16* b10 = W0 + (size_t)((g0 + 1) * 512 + wcol + row_a) * 544 + kq8;
      const _Float16* b11 = W0 + (size_t)((g0 + 1) * 512 + wcol + 16 + row_a) * 544 + kq8;
#pragma unroll 2
      for (int k0 = 0; k0 < 512; k0 += 32) {
        half8 a = *(const half8*)(&H0S(row_a, k0 + kq8));
        a0[g0][0]     = MFMA16(a, *(const half8*)(b00 + k0), a0[g0][0]);
        a0[g0][1]     = MFMA16(a, *(const half8*)(b01 + k0), a0[g0][1]);
        a0[g0 + 1][0] = MFMA16(a, *(const half8*)(b10 + k0), a0[g0 + 1][0]);
        a0[g0 + 1][1] = MFMA16(a, *(const half8*)(b11 + k0), a0[g0 + 1][1]);
      }
      // x part: K chunk at weight offset 512 (Wih0, 32 wide)
      a0[g0][0]     = MFMA16(ax, *(const half8*)(b00 + 512), a0[g0][0]);
      a0[g0][1]     = MFMA16(ax, *(const half8*)(b01 + 512), a0[g0][1]);
      a0[g0 + 1][0] = MFMA16(ax, *(const half8*)(b10 + 512), a0[g0 + 1][0]);
      a0[g0 + 1][1] = MFMA16(ax, *(const half8*)(b11 + 512), a0[g0 + 1][1]);
    }
    __syncthreads();   // all waves finished reading h0s (and xls)
    // L0 epilogue: c0, h0 (wave-local; D row = kq*4+j, col = wcol+nt*16+row_a)
#pragma unroll
    for (int nt = 0; nt < 2; ++nt)
#pragma unroll
      for (int j = 0; j < 4; ++j) {
        float iv = a0[0][nt][j], fv = a0[1][nt][j], gv = a0[2][nt][j], ov = a0[3][nt][j];
        float cn = sigf(fv) * c0r[nt][j] + sigf(iv) * tanhf_(gv);
        c0r[nt][j] = cn;
        H0S(kq * 4 + j, wcol + nt * 16 + row_a) = (_Float16)(sigf(ov) * tanhf_(cn));
      }
    __syncthreads();   // h0(t) visible to all waves

    // ---- L1: z1 = h1_prev @ Whh1^T + h0_new @ Wih1^T ----
    floatx4 a1[4][2];
#pragma unroll
    for (int g = 0; g < 4; ++g)
#pragma unroll
      for (int nt = 0; nt < 2; ++nt) {
        float b = bs1[g * 512 + wcol + nt * 16 + row_a];
        a1[g][nt] = (floatx4){b, b, b, b};
      }
#pragma unroll
    for (int gp = 0; gp < 2; ++gp) {
      const int g0 = gp * 2;
      const _Float16* b00 = W1 + (size_t)(g0 * 512 + wcol + row_a) * 1024 + kq8;
      const _Float16* b01 = W1 + (size_t)(g0 * 512 + wcol + 16 + row_a) * 1024 + kq8;
      const _Float16* b10 = W1 + (size_t)((g0 + 1) * 512 + wcol + row_a) * 1024 + kq8;
      const _Float16* b11 = W1 + (size_t)((g0 + 1) * 512 + wcol + 16 + row_a) * 1024 + kq8;
#pragma unroll 2
      for (int k0 = 0; k0 < 512; k0 += 32) {   // k 0..511: h1_prev
        half8 a = *(const half8*)(&H1S(row_a, k0 + kq8));
        a1[g0][0]     = MFMA16(a, *(const half8*)(b00 + k0), a1[g0][0]);
        a1[g0][1]     = MFMA16(a, *(const half8*)(b01 + k0), a1[g0][1]);
        a1[g0 + 1][0] = MFMA16(a, *(const half8*)(b10 + k0), a1[g0 + 1][0]);
        a1[g0 + 1][1] = MFMA16(a, *(const half8*)(b11 + k0), a1[g0 + 1][1]);
      }
#pragma unroll 2
      for (int k0 = 0; k0 < 512; k0 += 32) {   // k 512..1023: h0_new
        half8 a = *(const half8*)(&H0S(row_a, k0 + kq8));
        a1[g0][0]     = MFMA16(a, *(const half8*)(b00 + 512 + k0), a1[g0][0]);
        a1[g0][1]     = MFMA16(a, *(const half8*)(b01 + 512 + k0), a1[g0][1]);
        a1[g0 + 1][0] = MFMA16(a, *(const half8*)(b10 + 512 + k0), a1[g0 + 1][0]);
        a1[g0 + 1][1] = MFMA16(a, *(const half8*)(b11 + 512 + k0), a1[g0 + 1][1]);
      }
    }
    __syncthreads();   // all waves finished reading h1s (old)
    // L1 epilogue
#pragma unroll
    for (int nt = 0; nt < 2; ++nt)
#pragma unroll
      for (int j = 0; j < 4; ++j) {
        float iv = a1[0][nt][j], fv = a1[1][nt][j], gv = a1[2][nt][j], ov = a1[3][nt][j];
        float cn = sigf(fv) * c1r[nt][j] + sigf(iv) * tanhf_(gv);
        c1r[nt][j] = cn;
        H1S(kq * 4 + j, wcol + nt * 16 + row_a) = (_Float16)(sigf(ov) * tanhf_(cn));
      }
    __syncthreads();   // h1(t) visible

    // ---- decoder FC heads (block-local): x(d+1) = fc4(h1), out = fc1(h1) ----
    if (!enc) {
      const int d = s - 96;
      if (wv == 0) {           // fc4 -> xls (cols 0..31)
        floatx4 fa[2];
#pragma unroll
        for (int nt = 0; nt < 2; ++nt) {
          float b = bfc[nt * 16 + row_a];
          fa[nt] = (floatx4){b, b, b, b};
        }
        const _Float16* w0p = Wfc + (size_t)(row_a) * 512 + kq8;
        const _Float16* w1p = Wfc + (size_t)(16 + row_a) * 512 + kq8;
#pragma unroll 2
        for (int k0 = 0; k0 < 512; k0 += 32) {
          half8 a = *(const half8*)(&H1S(row_a, k0 + kq8));
          fa[0] = MFMA16(a, *(const half8*)(w0p + k0), fa[0]);
          fa[1] = MFMA16(a, *(const half8*)(w1p + k0), fa[1]);
        }
#pragma unroll
        for (int nt = 0; nt < 2; ++nt)
#pragma unroll
          for (int j = 0; j < 4; ++j)
            XLS(kq * 4 + j, nt * 16 + row_a) = (_Float16)fa[nt][j];
      } else if (wv == 1) {    // fc1 -> out (col 32 of padded Wfc)
        float b = bfc[32 + row_a];
        floatx4 fa = (floatx4){b, b, b, b};
        const _Float16* wp = Wfc + (size_t)(32 + row_a) * 512 + kq8;
#pragma unroll 2
        for (int k0 = 0; k0 < 512; k0 += 32) {
          half8 a = *(const half8*)(&H1S(row_a, k0 + kq8));
          fa = MFMA16(a, *(const half8*)(wp + k0), fa);
        }
        if (row_a == 0) {
#pragma unroll
          for (int j = 0; j < 4; ++j)
            out[(size_t)(row0 + kq * 4 + j) * 24 + d] = fa[j];
        }
      }
      __syncthreads();   // xls ready for next step's L0
    }
  }
}

// ---------------- host ----------------
extern "C" void kernel_launch(void* const* d_in, const int* in_sizes, int n_in,
                              void* d_out, int out_size, void* d_ws, size_t ws_size,
                              hipStream_t stream)
{
  const int base = (in_sizes[2] == 1) ? 3 : 2;
  const float* src   = (const float*)d_in[0];
  const float* eWih0 = (const float*)d_in[base + 0];
  const float* eWhh0 = (const float*)d_in[base + 1];
  const float* ebih0 = (const float*)d_in[base + 2];
  const float* ebhh0 = (const float*)d_in[base + 3];
  const float* eWih1 = (const float*)d_in[base + 4];
  const float* eWhh1 = (const float*)d_in[base + 5];
  const float* ebih1 = (const float*)d_in[base + 6];
  const float* ebhh1 = (const float*)d_in[base + 7];
  const float* dWih0 = (const float*)d_in[base + 8];
  const float* dWhh0 = (const float*)d_in[base + 9];
  const float* dbih0 = (const float*)d_in[base + 10];
  const float* dbhh0 = (const float*)d_in[base + 11];
  const float* dWih1 = (const float*)d_in[base + 12];
  const float* dWhh1 = (const float*)d_in[base + 13];
  const float* dbih1 = (const float*)d_in[base + 14];
  const float* dbhh1 = (const float*)d_in[base + 15];
  const float* fc1w  = (const float*)d_in[base + 16];
  const float* fc1b  = (const float*)d_in[base + 17];
  const float* fc4w  = (const float*)d_in[base + 18];
  const float* fc4b  = (const float*)d_in[base + 19];

  char* p = (char*)d_ws;
  _Float16* W0e = (_Float16*)p; p += 2048 * 544 * 2;
  _Float16* W1e = (_Float16*)p; p += 2048 * 1024 * 2;
  _Float16* W0d = (_Float16*)p; p += 2048 * 544 * 2;
  _Float16* W1d = (_Float16*)p; p += 2048 * 1024 * 2;
  float*    bsv = (float*)p;    p += 8192 * 4;
  _Float16* Xe  = (_Float16*)p; p += 96 * 512 * 32 * 2;
  _Float16* Wfc = (_Float16*)p; p += 48 * 512 * 2;
  float*    bfc = (float*)p;    p += 64 * 4;

  hipLaunchKernelGGL(prep_kernel, dim3(1024), dim3(256), 0, stream,
      src, eWih0, eWhh0, ebih0, ebhh0, eWih1, eWhh1, ebih1, ebhh1,
      dWih0, dWhh0, dbih0, dbhh0, dWih1, dWhh1, dbih1, dbhh1,
      fc1w, fc1b, fc4w, fc4b,
      W0e, W1e, W0d, W1d, bsv, Xe, Wfc, bfc);

  hipLaunchKernelGGL(lstm_main, dim3(NBLK), dim3(NTHR), 0, stream,
      W0e, W1e, W0d, W1d, bsv, Xe, Wfc, bfc, (float*)d_out);
}